// Round 9
// baseline (744.236 us; speedup 1.0000x reference)
//
#include <hip/hip_runtime.h>
#include <hip/hip_bf16.h>

#define NGRAPHS 512
#define BCAP 8192

typedef __attribute__((ext_vector_type(8))) short bf16x8;
typedef __attribute__((ext_vector_type(4))) float f32x4;

__device__ inline short f2bf(float x) {
    __hip_bfloat16 h = __float2bfloat16(x);
    return *(short*)&h;
}
__device__ inline float bflo(uint v) { return __uint_as_float(v << 16); }
__device__ inline float bfhi(uint v) { return __uint_as_float(v & 0xffff0000u); }

// Activation layout: slice-major [8][n][16ch] bf16. Slice s = channels [16s,16s+16).
// A 16-ch slice of the whole node table is 3.2 MB -> fits one XCD's 4 MB L2.

// ---------------- bucket-sort CSR build ----------------

__global__ __launch_bounds__(256) void k_bscatter(const int* __restrict__ src,
                                                  const int* __restrict__ dst,
                                                  int* __restrict__ bcur,
                                                  uint* __restrict__ pairs,
                                                  int nE, int NB) {
    __shared__ int cnt[512];
    __shared__ int gbase[512];
    const int t = threadIdx.x;
    const int seg0 = blockIdx.x * 4096;

    for (int l = t; l < NB; l += 256) cnt[l] = 0;
    __syncthreads();

    int sv[16], bv[16], rv[16];
#pragma unroll
    for (int k = 0; k < 16; ++k) {
        int e = seg0 + k * 256 + t;
        if (e < nE) {
            int d = dst[e];
            bv[k] = d >> 8;
            rv[k] = atomicAdd(&cnt[bv[k]], 1);
            sv[k] = src[e] | ((d & 255) << 20);
        } else {
            bv[k] = -1;
        }
    }
    __syncthreads();
    for (int l = t; l < NB; l += 256) {
        int c = cnt[l];
        gbase[l] = (c > 0) ? atomicAdd(&bcur[l], c) : 0;
    }
    __syncthreads();
#pragma unroll
    for (int k = 0; k < 16; ++k) {
        if (bv[k] >= 0) {
            int pos = gbase[bv[k]] + rv[k];
            if (pos < BCAP) pairs[(size_t)bv[k] * BCAP + pos] = (uint)sv[k];
        }
    }
}

__global__ __launch_bounds__(256) void k_bbuild(const int* __restrict__ bcur,
                                                const uint* __restrict__ pairs,
                                                int* __restrict__ row_start,
                                                int* __restrict__ row_end,
                                                float* __restrict__ rdeg,
                                                int* __restrict__ col, int n) {
    __shared__ int s[256];
    __shared__ int cur[256];
    const int b = blockIdx.x;
    const int t = threadIdx.x;
    const uint* bp = pairs + (size_t)b * BCAP;
    int cnt = bcur[b];
    if (cnt > BCAP) cnt = BCAP;

    s[t] = 0;
    __syncthreads();
    for (int i = t; i < cnt; i += 256) {
        int local = bp[i] >> 20;
        atomicAdd(&s[local], 1);
    }
    __syncthreads();
    int my = s[t];
    for (int off = 1; off < 256; off <<= 1) {
        int v = (t >= off) ? s[t - off] : 0;
        __syncthreads();
        s[t] += v;
        __syncthreads();
    }
    int excl = s[t] - my;
    int v = b * 256 + t;
    if (v < n) {
        row_start[v] = b * BCAP + excl;
        row_end[v] = b * BCAP + excl + my;
        rdeg[v] = 1.0f / (float)(my > 1 ? my : 1);
    }
    cur[t] = excl;
    __syncthreads();
    for (int i = t; i < cnt; i += 256) {
        uint u = bp[i];
        int local = u >> 20;
        int pos = atomicAdd(&cur[local], 1);
        col[(size_t)b * BCAP + pos] = (int)(u & 0xFFFFFu);
    }
}

// ---------------- f32 -> bf16 cast, sliced output ----------------

__global__ __launch_bounds__(256) void k_cast(const float* __restrict__ x,
                                              ushort* __restrict__ xb, int n) {
    int i = blockIdx.x * 256 + threadIdx.x;
    if (i >= n * 32) return;
    int node = i >> 5, chq = i & 31;           // 4-ch quad
    int s = chq >> 2, c4 = (chq & 3) * 4;
    float4 v = *(const float4*)(x + (size_t)node * 128 + chq * 4);
    ushort4 o;
    o.x = (ushort)f2bf(v.x);
    o.y = (ushort)f2bf(v.y);
    o.z = (ushort)f2bf(v.z);
    o.w = (ushort)f2bf(v.w);
    *(ushort4*)(xb + ((size_t)s * n + node) * 16 + c4) = o;
}

// ---------------- sliced mean aggregation ----------------
// block: slice s = blockIdx&7, 4 waves = 4 nodes. Wave: eg=lane>>3 picks 1 of 8
// edges, chh=lane&7 covers the 16-ch slice (uint = 2ch). Butterfly xor 8/16/32.

__global__ __launch_bounds__(256) void k_aggs(const ushort* __restrict__ hs,
                                              const int* __restrict__ row_start,
                                              const int* __restrict__ row_end,
                                              const int* __restrict__ col,
                                              const float* __restrict__ rdeg,
                                              ushort* __restrict__ outs, int n) {
    int blk = blockIdx.x;
    int s = blk & 7;
    int w = (blk >> 3) * 4 + (threadIdx.x >> 6);
    if (w >= n) return;
    int lane = threadIdx.x & 63;
    int eg = lane >> 3, chh = lane & 7;
    int b0 = row_start[w], e = row_end[w];
    float a0 = 0.f, a1 = 0.f;
    const ushort* base = hs + (size_t)s * n * 16;

    if (e > b0) {
        int cfirst = col[b0];
        for (int j = b0; j < e; j += 8) {
            int jj = j + eg;
            bool ok = jj < e;
            int c = ok ? col[jj] : cfirst;
            uint v = *(const uint*)(base + (size_t)c * 16 + chh * 2);
            if (ok) { a0 += bflo(v); a1 += bfhi(v); }
        }
        a0 += __shfl_xor(a0, 8);  a1 += __shfl_xor(a1, 8);
        a0 += __shfl_xor(a0, 16); a1 += __shfl_xor(a1, 16);
        a0 += __shfl_xor(a0, 32); a1 += __shfl_xor(a1, 32);
    }
    if (eg == 0) {
        float r = rdeg[w];
        uint o = (uint)(ushort)f2bf(a0 * r) | ((uint)(ushort)f2bf(a1 * r) << 16);
        *(uint*)(outs + ((size_t)s * n + w) * 16 + chh * 2) = o;
    }
}

// ---------------- sliced layer-2 aggregation on t2 = [tn|ts] ----------------
// tn = slices 0..3, ts = slices 4..7. out h3 flat [n][64].

__global__ __launch_bounds__(256) void k_agg2s(const ushort* __restrict__ t2s,
                                               const int* __restrict__ row_start,
                                               const int* __restrict__ row_end,
                                               const int* __restrict__ col,
                                               const float* __restrict__ rdeg,
                                               ushort* __restrict__ out, int n) {
    int blk = blockIdx.x;
    int s = blk & 3;
    int w = (blk >> 2) * 4 + (threadIdx.x >> 6);
    if (w >= n) return;
    int lane = threadIdx.x & 63;
    int eg = lane >> 3, chh = lane & 7;
    int b0 = row_start[w], e = row_end[w];
    float a0 = 0.f, a1 = 0.f;
    const ushort* base = t2s + (size_t)s * n * 16;

    if (e > b0) {
        int cfirst = col[b0];
        for (int j = b0; j < e; j += 8) {
            int jj = j + eg;
            bool ok = jj < e;
            int c = ok ? col[jj] : cfirst;
            uint v = *(const uint*)(base + (size_t)c * 16 + chh * 2);
            if (ok) { a0 += bflo(v); a1 += bfhi(v); }
        }
        a0 += __shfl_xor(a0, 8);  a1 += __shfl_xor(a1, 8);
        a0 += __shfl_xor(a0, 16); a1 += __shfl_xor(a1, 16);
        a0 += __shfl_xor(a0, 32); a1 += __shfl_xor(a1, 32);
    }
    if (eg == 0) {
        float r = rdeg[w];
        uint tv = *(const uint*)(t2s + ((size_t)(s + 4) * n + w) * 16 + chh * 2);
        float v0 = a0 * r + bflo(tv);
        float v1 = a1 * r + bfhi(tv);
        uint o = (uint)(ushort)f2bf(v0) | ((uint)(ushort)f2bf(v1) << 16);
        *(uint*)(out + (size_t)w * 64 + s * 16 + chh * 2) = o;
    }
}

// ---------------- weight prep ----------------

__global__ void k_wprep(const float* __restrict__ wn, const float* __restrict__ ws,
                        short* __restrict__ whi, short* __restrict__ wlo, int outc) {
    int i = blockIdx.x * 256 + threadIdx.x;
    if (i >= outc * 256) return;
    int c = i >> 8, k = i & 255;
    float w = (k < 128) ? wn[c * 128 + k] : ws[c * 128 + k - 128];
    short hi = f2bf(w);
    __hip_bfloat16 hb = *(__hip_bfloat16*)&hi;
    float hif = __bfloat162float(hb);
    whi[i] = hi;
    wlo[i] = f2bf(w - hif);
}

__global__ void k_wprep2(const float* __restrict__ wn, const float* __restrict__ ws,
                         short* __restrict__ whi, short* __restrict__ wlo) {
    int i = blockIdx.x * 256 + threadIdx.x;
    if (i >= 128 * 128) return;
    int c = i >> 7, k = i & 127;
    float w = (c < 64) ? wn[c * 128 + k] : ws[(c - 64) * 128 + k];
    short hi = f2bf(w);
    __hip_bfloat16 hb = *(__hip_bfloat16*)&hi;
    float hif = __bfloat162float(hb);
    whi[i] = hi;
    wlo[i] = f2bf(w - hif);
}

// ---------------- pipelined LDS-staged MFMA transform (sliced I/O) ----------------

template <int KH>
__device__ inline uint4 loadA(const ushort* __restrict__ meanbuf,
                              const ushort* __restrict__ hbuf, int n, int m, int seg) {
    uint4 R;
    if constexpr (KH == 2) {
        const ushort* sp = (seg < 16)
            ? (meanbuf + ((size_t)(seg >> 1) * n + m) * 16 + (seg & 1) * 8)
            : (hbuf + ((size_t)((seg - 16) >> 1) * n + m) * 16 + ((seg - 16) & 1) * 8);
        R = *(const uint4*)sp;
    } else {
        uint2 r2 = *(const uint2*)(hbuf + ((size_t)(seg >> 2) * n + m) * 16 + (seg & 3) * 4);
        R.x = r2.x; R.y = r2.y; R.z = 0; R.w = 0;
    }
    return R;
}

template <int KH, bool RELU, bool HALFBIAS, int CHUNK>
__global__ __launch_bounds__(512) void k_transform2(
    const ushort* __restrict__ meanbuf, const ushort* __restrict__ hbuf,
    const bf16x8* __restrict__ whi, const bf16x8* __restrict__ wlo,
    const float* __restrict__ bias, ushort* __restrict__ out, int n, int nTiles) {
    constexpr int ROWB = KH * 256;
    constexpr int KS = KH * 4;
    __shared__ ushort lds[2][16 * KH * 128];

    const int t = threadIdx.x;
    const int wave = t >> 6, lane = t & 63;
    const int lmod = lane & 15, lgrp = lane >> 4;
    const int c = wave * 16 + lmod;

    bf16x8 bh[KS], bl[KS];
#pragma unroll
    for (int ks = 0; ks < KS; ++ks) {
        int idx = c * (KH * 16) + ks * 4 + lgrp;
        bh[ks] = whi[idx];
        bl[ks] = wlo[idx];
    }
    float bv;
    if (HALFBIAS) bv = (c >= 64) ? bias[c - 64] : 0.f;
    else bv = bias[c];

    const int srow = t >> 5;
    const int seg = t & 31;
    const int tile0 = blockIdx.x * CHUNK;
    if (tile0 >= nTiles) return;
    const int nt = (nTiles - tile0 < CHUNK) ? (nTiles - tile0) : CHUNK;
    const int swr = (srow * ROWB + seg * (KH == 2 ? 16 : 8)) ^ ((srow & 7) << 4);

    uint4 R;
    {
        int m = tile0 * 16 + srow; if (m >= n) m = n - 1;
        R = loadA<KH>(meanbuf, hbuf, n, m, seg);
    }
    if constexpr (KH == 2) *(uint4*)((char*)lds[0] + swr) = R;
    else { uint2 r2; r2.x = R.x; r2.y = R.y; *(uint2*)((char*)lds[0] + swr) = r2; }
    {
        int m = (tile0 + 1) * 16 + srow; if (m >= n) m = n - 1;
        R = loadA<KH>(meanbuf, hbuf, n, m, seg);
    }

    for (int tt = 0; tt < nt; ++tt) {
        __syncthreads();
        if (tt + 1 < nt) {
            if constexpr (KH == 2) *(uint4*)((char*)lds[(tt + 1) & 1] + swr) = R;
            else { uint2 r2; r2.x = R.x; r2.y = R.y; *(uint2*)((char*)lds[(tt + 1) & 1] + swr) = r2; }
        }
        if (tt + 2 < nt) {
            int m = (tile0 + tt + 2) * 16 + srow; if (m >= n) m = n - 1;
            R = loadA<KH>(meanbuf, hbuf, n, m, seg);
        }

        bf16x8 af[KS];
#pragma unroll
        for (int ks = 0; ks < KS; ++ks) {
            int byte = (lmod * ROWB + ks * 64 + lgrp * 16) ^ ((lmod & 7) << 4);
            af[ks] = *(const bf16x8*)((const char*)lds[tt & 1] + byte);
        }
        f32x4 ah = {0.f, 0.f, 0.f, 0.f}, al = {0.f, 0.f, 0.f, 0.f};
#pragma unroll
        for (int ks = 0; ks < KS; ++ks) {
            ah = __builtin_amdgcn_mfma_f32_16x16x32_bf16(af[ks], bh[ks], ah, 0, 0, 0);
            al = __builtin_amdgcn_mfma_f32_16x16x32_bf16(af[ks], bl[ks], al, 0, 0, 0);
        }
        int row0 = (tile0 + tt) * 16;
        // sliced output: wave w owns cols [16w,16w+16) = slice w
#pragma unroll
        for (int r = 0; r < 4; ++r) {
            int rr = row0 + lgrp * 4 + r;
            float v = ah[r] + al[r] + bv;
            if (RELU) v = fmaxf(v, 0.f);
            if (rr < n) out[((size_t)wave * n + rr) * 16 + lmod] = (ushort)f2bf(v);
        }
    }
}

// ---------------- pool ----------------

__global__ void k_gbounds(const int* __restrict__ batch, int* __restrict__ gstart, int n) {
    int g = blockIdx.x * blockDim.x + threadIdx.x;
    if (g > NGRAPHS) return;
    int lo = 0, hi = n;
    while (lo < hi) {
        int mid = (lo + hi) >> 1;
        if (batch[mid] < g) lo = mid + 1; else hi = mid;
    }
    gstart[g] = lo;
}

__global__ __launch_bounds__(256) void k_pool2(const ushort* __restrict__ h,
                                               const int* __restrict__ gstart,
                                               float* __restrict__ out) {
    int g = blockIdx.x;
    int t = threadIdx.x, lane = t & 63, wv = t >> 6;
    int s = gstart[g], e = gstart[g + 1];
    float acc = 0.f;
    for (int i = s + wv; i < e; i += 4) {
        uint v = h[(size_t)i * 64 + lane];
        acc += __uint_as_float(v << 16);
    }
    __shared__ float red[4][64];
    red[wv][lane] = acc;
    __syncthreads();
    if (wv == 0) {
        float tot = red[0][lane] + red[1][lane] + red[2][lane] + red[3][lane];
        float c = (float)(e - s);
        out[g * 64 + lane] = tot / fmaxf(c, 1.0f);
    }
}

// ---------------- launcher ----------------

extern "C" void kernel_launch(void* const* d_in, const int* in_sizes, int n_in,
                              void* d_out, int out_size, void* d_ws, size_t ws_size,
                              hipStream_t stream) {
    const float* x = (const float*)d_in[0];
    const int* ei = (const int*)d_in[1];
    const int* batch = (const int*)d_in[2];
    const float* wn0 = (const float*)d_in[3];
    const float* ws0 = (const float*)d_in[4];
    const float* b0 = (const float*)d_in[5];
    const float* wn1 = (const float*)d_in[6];
    const float* ws1 = (const float*)d_in[7];
    const float* b1 = (const float*)d_in[8];
    const float* wn2 = (const float*)d_in[9];
    const float* ws2 = (const float*)d_in[10];
    const float* b2 = (const float*)d_in[11];

    const int n = in_sizes[0] / 128;  // 100000
    const int nE = in_sizes[1] / 2;   // 1600000
    const int* src = ei;
    const int* dst = ei + nE;
    const int NB = (n + 255) >> 8;    // 391 buckets

    char* p = (char*)d_ws;
    auto alloc = [&](size_t bytes) {
        void* r = (void*)p;
        p += (bytes + 255) & ~(size_t)255;
        return r;
    };
    int* bcur = (int*)alloc((size_t)NB * 4);
    uint* pairs = (uint*)alloc((size_t)NB * BCAP * 4);
    int* col = (int*)alloc((size_t)NB * BCAP * 4);
    int* row_start = (int*)alloc((size_t)NB * 256 * 4);
    int* row_end = (int*)alloc((size_t)NB * 256 * 4);
    float* rdeg = (float*)alloc((size_t)NB * 256 * 4);
    int* gstart = (int*)alloc((size_t)(NGRAPHS + 1) * 4);
    short* whi0 = (short*)alloc(128 * 256 * 2);
    short* wlo0 = (short*)alloc(128 * 256 * 2);
    short* whi1 = (short*)alloc(128 * 256 * 2);
    short* wlo1 = (short*)alloc(128 * 256 * 2);
    short* whi2 = (short*)alloc(128 * 128 * 2);
    short* wlo2 = (short*)alloc(128 * 128 * 2);
    ushort* xb = (ushort*)alloc((size_t)n * 128 * 2);     // sliced [8][n][16]
    ushort* meanb = (ushort*)alloc((size_t)n * 128 * 2);  // sliced; reused as t2
    ushort* h1 = (ushort*)alloc((size_t)n * 128 * 2);     // sliced
    ushort* h2 = (ushort*)alloc((size_t)n * 128 * 2);     // sliced
    ushort* h3 = (ushort*)alloc((size_t)n * 64 * 2);      // flat

    (void)hipMemsetAsync(bcur, 0, (size_t)NB * 4, stream);

    const int tb = 256;

    k_bscatter<<<(nE + 4095) / 4096, tb, 0, stream>>>(src, dst, bcur, pairs, nE, NB);
    k_bbuild<<<NB, tb, 0, stream>>>(bcur, pairs, row_start, row_end, rdeg, col, n);

    k_cast<<<((n * 32) + 255) / 256, 256, 0, stream>>>(x, xb, n);

    k_wprep<<<(128 * 256 + 255) / 256, 256, 0, stream>>>(wn0, ws0, whi0, wlo0, 128);
    k_wprep<<<(128 * 256 + 255) / 256, 256, 0, stream>>>(wn1, ws1, whi1, wlo1, 128);
    k_wprep2<<<(128 * 128 + 255) / 256, 256, 0, stream>>>(wn2, ws2, whi2, wlo2);

    k_gbounds<<<3, 256, 0, stream>>>(batch, gstart, n);

    const int npb4 = (n + 3) / 4;           // nodes per slice-pass / 4 waves
    const int aggGrid = 8 * npb4;           // slice = blockIdx & 7
    const int agg2Grid = 4 * npb4;          // slice = blockIdx & 3
    const int nTiles = (n + 15) / 16;
    const int CH = 13;
    const int tGrid = (nTiles + CH - 1) / CH;

    // layer 0
    k_aggs<<<aggGrid, tb, 0, stream>>>(xb, row_start, row_end, col, rdeg, meanb, n);
    k_transform2<2, true, false, 13><<<tGrid, 512, 0, stream>>>(
        meanb, xb, (const bf16x8*)whi0, (const bf16x8*)wlo0, b0, h1, n, nTiles);
    // layer 1
    k_aggs<<<aggGrid, tb, 0, stream>>>(h1, row_start, row_end, col, rdeg, meanb, n);
    k_transform2<2, true, false, 13><<<tGrid, 512, 0, stream>>>(
        meanb, h1, (const bf16x8*)whi1, (const bf16x8*)wlo1, b1, h2, n, nTiles);
    // layer 2 (commuted): t2 = h2 @ [Wn2;Ws2]^T -> meanb (sliced); then sliced agg2
    k_transform2<1, false, true, 13><<<tGrid, 512, 0, stream>>>(
        h2, h2, (const bf16x8*)whi2, (const bf16x8*)wlo2, b2, meanb, n, nTiles);
    k_agg2s<<<agg2Grid, tb, 0, stream>>>(meanb, row_start, row_end, col, rdeg, h3, n);

    // pool -> d_out
    k_pool2<<<NGRAPHS, 256, 0, stream>>>(h3, gstart, (float*)d_out);
}

// Round 10
// 363.396 us; speedup vs baseline: 2.0480x; 2.0480x over previous
//
#include <hip/hip_runtime.h>
#include <hip/hip_bf16.h>

#define NGRAPHS 512
#define BCAP 8192

typedef __attribute__((ext_vector_type(8))) short bf16x8;
typedef __attribute__((ext_vector_type(4))) float f32x4;

__device__ inline short f2bf(float x) {
    __hip_bfloat16 h = __float2bfloat16(x);
    return *(short*)&h;
}
__device__ inline float bflo(uint v) { return __uint_as_float(v << 16); }
__device__ inline float bfhi(uint v) { return __uint_as_float(v & 0xffff0000u); }

// ---------------- bucket-sort CSR build ----------------

__global__ __launch_bounds__(256) void k_bscatter(const int* __restrict__ src,
                                                  const int* __restrict__ dst,
                                                  int* __restrict__ bcur,
                                                  uint* __restrict__ pairs,
                                                  int nE, int NB) {
    __shared__ int cnt[512];
    __shared__ int gbase[512];
    const int t = threadIdx.x;
    const int seg0 = blockIdx.x * 4096;

    for (int l = t; l < NB; l += 256) cnt[l] = 0;
    __syncthreads();

    int sv[16], bv[16], rv[16];
#pragma unroll
    for (int k = 0; k < 16; ++k) {
        int e = seg0 + k * 256 + t;
        if (e < nE) {
            int d = dst[e];
            bv[k] = d >> 8;
            rv[k] = atomicAdd(&cnt[bv[k]], 1);
            sv[k] = src[e] | ((d & 255) << 20);
        } else {
            bv[k] = -1;
        }
    }
    __syncthreads();
    for (int l = t; l < NB; l += 256) {
        int c = cnt[l];
        gbase[l] = (c > 0) ? atomicAdd(&bcur[l], c) : 0;
    }
    __syncthreads();
#pragma unroll
    for (int k = 0; k < 16; ++k) {
        if (bv[k] >= 0) {
            int pos = gbase[bv[k]] + rv[k];
            if (pos < BCAP) pairs[(size_t)bv[k] * BCAP + pos] = (uint)sv[k];
        }
    }
}

// builds padded CSR; cols of each row SORTED ascending (L2 locality: all waves
// sweep the node table low->high in loose lockstep).

__global__ __launch_bounds__(256) void k_bbuild(const int* __restrict__ bcur,
                                                const uint* __restrict__ pairs,
                                                int* __restrict__ row_start,
                                                int* __restrict__ row_end,
                                                float* __restrict__ rdeg,
                                                int* __restrict__ col, int n) {
    __shared__ int s[256];
    __shared__ int cur[256];
    __shared__ int colbuf[BCAP];
    const int b = blockIdx.x;
    const int t = threadIdx.x;
    const uint* bp = pairs + (size_t)b * BCAP;
    int cnt = bcur[b];
    if (cnt > BCAP) cnt = BCAP;

    s[t] = 0;
    __syncthreads();
    for (int i = t; i < cnt; i += 256) {
        int local = bp[i] >> 20;
        atomicAdd(&s[local], 1);
    }
    __syncthreads();
    int my = s[t];
    for (int off = 1; off < 256; off <<= 1) {
        int v = (t >= off) ? s[t - off] : 0;
        __syncthreads();
        s[t] += v;
        __syncthreads();
    }
    int excl = s[t] - my;
    int v = b * 256 + t;
    if (v < n) {
        row_start[v] = b * BCAP + excl;
        row_end[v] = b * BCAP + excl + my;
        rdeg[v] = 1.0f / (float)(my > 1 ? my : 1);
    }
    cur[t] = excl;
    __syncthreads();
    for (int i = t; i < cnt; i += 256) {
        uint u = bp[i];
        int local = u >> 20;
        int pos = atomicAdd(&cur[local], 1);
        colbuf[pos] = (int)(u & 0xFFFFFu);
    }
    __syncthreads();
    // insertion-sort my row's segment [excl, excl+my) in LDS
    for (int a = excl + 1; a < excl + my; ++a) {
        int key = colbuf[a];
        int q = a - 1;
        while (q >= excl && colbuf[q] > key) { colbuf[q + 1] = colbuf[q]; --q; }
        colbuf[q + 1] = key;
    }
    __syncthreads();
    for (int i = t; i < cnt; i += 256) col[(size_t)b * BCAP + i] = colbuf[i];
}

// ---------------- f32 -> bf16 cast ----------------

__global__ __launch_bounds__(256) void k_cast(const float* __restrict__ x,
                                              ushort* __restrict__ xb, int total4) {
    int i = blockIdx.x * 256 + threadIdx.x;
    if (i >= total4) return;
    float4 v = ((const float4*)x)[i];
    ushort4 o;
    o.x = (ushort)f2bf(v.x);
    o.y = (ushort)f2bf(v.y);
    o.z = (ushort)f2bf(v.z);
    o.w = (ushort)f2bf(v.w);
    ((ushort4*)xb)[i] = o;
}

// ---------------- mean aggregation (128 ch) ----------------

__global__ __launch_bounds__(256) void k_agg(const ushort* __restrict__ h,
                                             const int* __restrict__ row_start,
                                             const int* __restrict__ row_end,
                                             const int* __restrict__ col,
                                             const float* __restrict__ rdeg,
                                             ushort* __restrict__ out, int n) {
    int w = (blockIdx.x * blockDim.x + threadIdx.x) >> 6;
    int lane = threadIdx.x & 63;
    if (w >= n) return;
    int s = row_start[w], e = row_end[w];
    int grp = lane >> 4;
    int cl = lane & 15;

    float a0 = 0.f, a1 = 0.f, a2 = 0.f, a3 = 0.f, a4 = 0.f, a5 = 0.f, a6 = 0.f, a7 = 0.f;

    if (e > s) {
        int cfirst = col[s];
        for (int j = s; j < e; j += 8) {
            int j0 = j + grp, j1 = j + 4 + grp;
            bool ok0 = j0 < e, ok1 = j1 < e;
            int c0 = ok0 ? col[j0] : cfirst;
            int c1 = ok1 ? col[j1] : cfirst;
            uint4 r0 = *(const uint4*)(h + (size_t)c0 * 128 + cl * 8);
            uint4 r1 = *(const uint4*)(h + (size_t)c1 * 128 + cl * 8);
            if (ok0) {
                a0 += bflo(r0.x); a1 += bfhi(r0.x);
                a2 += bflo(r0.y); a3 += bfhi(r0.y);
                a4 += bflo(r0.z); a5 += bfhi(r0.z);
                a6 += bflo(r0.w); a7 += bfhi(r0.w);
            }
            if (ok1) {
                a0 += bflo(r1.x); a1 += bfhi(r1.x);
                a2 += bflo(r1.y); a3 += bfhi(r1.y);
                a4 += bflo(r1.z); a5 += bfhi(r1.z);
                a6 += bflo(r1.w); a7 += bfhi(r1.w);
            }
        }
        a0 += __shfl_xor(a0, 16); a1 += __shfl_xor(a1, 16);
        a2 += __shfl_xor(a2, 16); a3 += __shfl_xor(a3, 16);
        a4 += __shfl_xor(a4, 16); a5 += __shfl_xor(a5, 16);
        a6 += __shfl_xor(a6, 16); a7 += __shfl_xor(a7, 16);
        a0 += __shfl_xor(a0, 32); a1 += __shfl_xor(a1, 32);
        a2 += __shfl_xor(a2, 32); a3 += __shfl_xor(a3, 32);
        a4 += __shfl_xor(a4, 32); a5 += __shfl_xor(a5, 32);
        a6 += __shfl_xor(a6, 32); a7 += __shfl_xor(a7, 32);
    }

    if (grp == 0) {
        float r = rdeg[w];
        uint4 o;
        o.x = (uint)(ushort)f2bf(a0 * r) | ((uint)(ushort)f2bf(a1 * r) << 16);
        o.y = (uint)(ushort)f2bf(a2 * r) | ((uint)(ushort)f2bf(a3 * r) << 16);
        o.z = (uint)(ushort)f2bf(a4 * r) | ((uint)(ushort)f2bf(a5 * r) << 16);
        o.w = (uint)(ushort)f2bf(a6 * r) | ((uint)(ushort)f2bf(a7 * r) << 16);
        *(uint4*)(out + (size_t)w * 128 + cl * 8) = o;
    }
}

// ---------------- layer-2 aggregation on t2 = [tn|ts] ----------------

__global__ __launch_bounds__(256) void k_agg2(const ushort* __restrict__ t2,
                                              const int* __restrict__ row_start,
                                              const int* __restrict__ row_end,
                                              const int* __restrict__ col,
                                              const float* __restrict__ rdeg,
                                              ushort* __restrict__ out, int n) {
    int w = (blockIdx.x * blockDim.x + threadIdx.x) >> 6;
    int lane = threadIdx.x & 63;
    if (w >= n) return;
    int s = row_start[w], e = row_end[w];
    int grp = lane >> 4;
    int cl = lane & 15;

    float a0 = 0.f, a1 = 0.f, a2 = 0.f, a3 = 0.f;

    if (e > s) {
        int cfirst = col[s];
        for (int j = s; j < e; j += 8) {
            int j0 = j + grp, j1 = j + 4 + grp;
            bool ok0 = j0 < e, ok1 = j1 < e;
            int c0 = ok0 ? col[j0] : cfirst;
            int c1 = ok1 ? col[j1] : cfirst;
            uint2 r0 = *(const uint2*)(t2 + (size_t)c0 * 128 + cl * 4);
            uint2 r1 = *(const uint2*)(t2 + (size_t)c1 * 128 + cl * 4);
            if (ok0) {
                a0 += bflo(r0.x); a1 += bfhi(r0.x);
                a2 += bflo(r0.y); a3 += bfhi(r0.y);
            }
            if (ok1) {
                a0 += bflo(r1.x); a1 += bfhi(r1.x);
                a2 += bflo(r1.y); a3 += bfhi(r1.y);
            }
        }
        a0 += __shfl_xor(a0, 16); a1 += __shfl_xor(a1, 16);
        a2 += __shfl_xor(a2, 16); a3 += __shfl_xor(a3, 16);
        a0 += __shfl_xor(a0, 32); a1 += __shfl_xor(a1, 32);
        a2 += __shfl_xor(a2, 32); a3 += __shfl_xor(a3, 32);
    }

    if (grp == 0) {
        float r = rdeg[w];
        uint2 tsv = *(const uint2*)(t2 + (size_t)w * 128 + 64 + cl * 4);
        float t0 = bflo(tsv.x), t1 = bfhi(tsv.x);
        float t2v = bflo(tsv.y), t3 = bfhi(tsv.y);
        uint2 o;
        o.x = (uint)(ushort)f2bf(a0 * r + t0) | ((uint)(ushort)f2bf(a1 * r + t1) << 16);
        o.y = (uint)(ushort)f2bf(a2 * r + t2v) | ((uint)(ushort)f2bf(a3 * r + t3) << 16);
        *(uint2*)(out + (size_t)w * 64 + cl * 4) = o;
    }
}

// ---------------- weight prep ----------------

__global__ void k_wprep(const float* __restrict__ wn, const float* __restrict__ ws,
                        short* __restrict__ whi, short* __restrict__ wlo, int outc) {
    int i = blockIdx.x * 256 + threadIdx.x;
    if (i >= outc * 256) return;
    int c = i >> 8, k = i & 255;
    float w = (k < 128) ? wn[c * 128 + k] : ws[c * 128 + k - 128];
    short hi = f2bf(w);
    __hip_bfloat16 hb = *(__hip_bfloat16*)&hi;
    float hif = __bfloat162float(hb);
    whi[i] = hi;
    wlo[i] = f2bf(w - hif);
}

__global__ void k_wprep2(const float* __restrict__ wn, const float* __restrict__ ws,
                         short* __restrict__ whi, short* __restrict__ wlo) {
    int i = blockIdx.x * 256 + threadIdx.x;
    if (i >= 128 * 128) return;
    int c = i >> 7, k = i & 127;
    float w = (c < 64) ? wn[c * 128 + k] : ws[(c - 64) * 128 + k];
    short hi = f2bf(w);
    __hip_bfloat16 hb = *(__hip_bfloat16*)&hi;
    float hif = __bfloat162float(hb);
    whi[i] = hi;
    wlo[i] = f2bf(w - hif);
}

// ---------------- pipelined LDS-staged MFMA transform (layer 0) ----------------

template <bool RELU, int CHUNK>
__global__ __launch_bounds__(512) void k_transform2(
    const ushort* __restrict__ meanbuf, const ushort* __restrict__ hbuf,
    const bf16x8* __restrict__ whi, const bf16x8* __restrict__ wlo,
    const float* __restrict__ bias, ushort* __restrict__ out, int n, int nTiles) {
    constexpr int ROWB = 512;
    __shared__ ushort lds[2][16 * 256];

    const int t = threadIdx.x;
    const int wave = t >> 6, lane = t & 63;
    const int lmod = lane & 15, lgrp = lane >> 4;
    const int c = wave * 16 + lmod;

    bf16x8 bh[8], bl[8];
#pragma unroll
    for (int ks = 0; ks < 8; ++ks) {
        int idx = c * 32 + ks * 4 + lgrp;
        bh[ks] = whi[idx];
        bl[ks] = wlo[idx];
    }
    float bv = bias[c];

    const int srow = t >> 5;
    const int seg = t & 31;
    const int tile0 = blockIdx.x * CHUNK;
    if (tile0 >= nTiles) return;
    const int nt = (nTiles - tile0 < CHUNK) ? (nTiles - tile0) : CHUNK;
    const int swr = (srow * ROWB + seg * 16) ^ ((srow & 7) << 4);

    uint4 R;
    {
        int m = tile0 * 16 + srow; if (m >= n) m = n - 1;
        const ushort* sp = (seg < 16) ? (meanbuf + (size_t)m * 128 + seg * 8)
                                      : (hbuf + (size_t)m * 128 + (seg - 16) * 8);
        R = *(const uint4*)sp;
    }
    *(uint4*)((char*)lds[0] + swr) = R;
    {
        int m = (tile0 + 1) * 16 + srow; if (m >= n) m = n - 1;
        const ushort* sp = (seg < 16) ? (meanbuf + (size_t)m * 128 + seg * 8)
                                      : (hbuf + (size_t)m * 128 + (seg - 16) * 8);
        R = *(const uint4*)sp;
    }

    for (int tt = 0; tt < nt; ++tt) {
        __syncthreads();
        if (tt + 1 < nt) *(uint4*)((char*)lds[(tt + 1) & 1] + swr) = R;
        if (tt + 2 < nt) {
            int m = (tile0 + tt + 2) * 16 + srow; if (m >= n) m = n - 1;
            const ushort* sp = (seg < 16) ? (meanbuf + (size_t)m * 128 + seg * 8)
                                          : (hbuf + (size_t)m * 128 + (seg - 16) * 8);
            R = *(const uint4*)sp;
        }

        bf16x8 af[8];
#pragma unroll
        for (int ks = 0; ks < 8; ++ks) {
            int byte = (lmod * ROWB + ks * 64 + lgrp * 16) ^ ((lmod & 7) << 4);
            af[ks] = *(const bf16x8*)((const char*)lds[tt & 1] + byte);
        }
        f32x4 ah = {0.f, 0.f, 0.f, 0.f}, al = {0.f, 0.f, 0.f, 0.f};
#pragma unroll
        for (int ks = 0; ks < 8; ++ks) {
            ah = __builtin_amdgcn_mfma_f32_16x16x32_bf16(af[ks], bh[ks], ah, 0, 0, 0);
            al = __builtin_amdgcn_mfma_f32_16x16x32_bf16(af[ks], bl[ks], al, 0, 0, 0);
        }
        int row0 = (tile0 + tt) * 16;
#pragma unroll
        for (int r = 0; r < 4; ++r) {
            int rr = row0 + lgrp * 4 + r;
            float v = ah[r] + al[r] + bv;
            if (RELU) v = fmaxf(v, 0.f);
            if (rr < n) out[(size_t)rr * 128 + c] = (ushort)f2bf(v);
        }
    }
}

// ---------------- fused layer-1 transform + commuted layer-2 transform ----------------
// stage 1: h2 = relu([mean1|h1] @ W1cat^T + b1)  (K=256) -> swizzled LDS tile
// stage 2: t2 = h2 @ W2cat^T (+b2 on ts half)    (K=128) -> global [n][128]

template <int CHUNK>
__global__ __launch_bounds__(512) void k_transform_fused(
    const ushort* __restrict__ meanbuf, const ushort* __restrict__ hbuf,
    const bf16x8* __restrict__ whi1, const bf16x8* __restrict__ wlo1,
    const float* __restrict__ bias1,
    const bf16x8* __restrict__ whi2, const bf16x8* __restrict__ wlo2,
    const float* __restrict__ bias2,
    ushort* __restrict__ out, int n, int nTiles) {
    constexpr int ROWB = 512;
    __shared__ ushort lds[2][16 * 256];
    __shared__ ushort hlds[16 * 128];

    const int t = threadIdx.x;
    const int wave = t >> 6, lane = t & 63;
    const int lmod = lane & 15, lgrp = lane >> 4;
    const int c = wave * 16 + lmod;

    bf16x8 b1h[8], b1l[8], b2h[4], b2l[4];
#pragma unroll
    for (int ks = 0; ks < 8; ++ks) {
        int idx = c * 32 + ks * 4 + lgrp;
        b1h[ks] = whi1[idx];
        b1l[ks] = wlo1[idx];
    }
#pragma unroll
    for (int ks = 0; ks < 4; ++ks) {
        int idx = c * 16 + ks * 4 + lgrp;
        b2h[ks] = whi2[idx];
        b2l[ks] = wlo2[idx];
    }
    float bv1 = bias1[c];
    float bv2 = (c >= 64) ? bias2[c - 64] : 0.f;

    const int srow = t >> 5;
    const int seg = t & 31;
    const int tile0 = blockIdx.x * CHUNK;
    if (tile0 >= nTiles) return;
    const int nt = (nTiles - tile0 < CHUNK) ? (nTiles - tile0) : CHUNK;
    const int swr = (srow * ROWB + seg * 16) ^ ((srow & 7) << 4);

    uint4 R;
    {
        int m = tile0 * 16 + srow; if (m >= n) m = n - 1;
        const ushort* sp = (seg < 16) ? (meanbuf + (size_t)m * 128 + seg * 8)
                                      : (hbuf + (size_t)m * 128 + (seg - 16) * 8);
        R = *(const uint4*)sp;
    }
    *(uint4*)((char*)lds[0] + swr) = R;
    {
        int m = (tile0 + 1) * 16 + srow; if (m >= n) m = n - 1;
        const ushort* sp = (seg < 16) ? (meanbuf + (size_t)m * 128 + seg * 8)
                                      : (hbuf + (size_t)m * 128 + (seg - 16) * 8);
        R = *(const uint4*)sp;
    }

    for (int tt = 0; tt < nt; ++tt) {
        __syncthreads();  // A buf ready; also protects hlds reuse (reads were pre-sync)
        if (tt + 1 < nt) *(uint4*)((char*)lds[(tt + 1) & 1] + swr) = R;
        if (tt + 2 < nt) {
            int m = (tile0 + tt + 2) * 16 + srow; if (m >= n) m = n - 1;
            const ushort* sp = (seg < 16) ? (meanbuf + (size_t)m * 128 + seg * 8)
                                          : (hbuf + (size_t)m * 128 + (seg - 16) * 8);
            R = *(const uint4*)sp;
        }

        // stage 1: K=256 MFMA
        bf16x8 af[8];
#pragma unroll
        for (int ks = 0; ks < 8; ++ks) {
            int byte = (lmod * ROWB + ks * 64 + lgrp * 16) ^ ((lmod & 7) << 4);
            af[ks] = *(const bf16x8*)((const char*)lds[tt & 1] + byte);
        }
        f32x4 ah = {0.f, 0.f, 0.f, 0.f}, al = {0.f, 0.f, 0.f, 0.f};
#pragma unroll
        for (int ks = 0; ks < 8; ++ks) {
            ah = __builtin_amdgcn_mfma_f32_16x16x32_bf16(af[ks], b1h[ks], ah, 0, 0, 0);
            al = __builtin_amdgcn_mfma_f32_16x16x32_bf16(af[ks], b1l[ks], al, 0, 0, 0);
        }
        // write h2 tile to swizzled LDS: row rr16 (0..15), col c
#pragma unroll
        for (int r = 0; r < 4; ++r) {
            int rr16 = lgrp * 4 + r;
            float v = fmaxf(ah[r] + al[r] + bv1, 0.f);
            int byte = ((rr16 * 256 + (c >> 3) * 16) ^ ((rr16 & 7) << 4)) + (c & 7) * 2;
            *(ushort*)((char*)hlds + byte) = (ushort)f2bf(v);
        }
        __syncthreads();  // h2 tile complete

        // stage 2: K=128 MFMA from hlds
        bf16x8 af2[4];
#pragma unroll
        for (int ks = 0; ks < 4; ++ks) {
            int byte = (lmod * 256 + ks * 64 + lgrp * 16) ^ ((lmod & 7) << 4);
            af2[ks] = *(const bf16x8*)((const char*)hlds + byte);
        }
        f32x4 ch = {0.f, 0.f, 0.f, 0.f}, cl2 = {0.f, 0.f, 0.f, 0.f};
#pragma unroll
        for (int ks = 0; ks < 4; ++ks) {
            ch = __builtin_amdgcn_mfma_f32_16x16x32_bf16(af2[ks], b2h[ks], ch, 0, 0, 0);
            cl2 = __builtin_amdgcn_mfma_f32_16x16x32_bf16(af2[ks], b2l[ks], cl2, 0, 0, 0);
        }
        int row0 = (tile0 + tt) * 16;
#pragma unroll
        for (int r = 0; r < 4; ++r) {
            int rr = row0 + lgrp * 4 + r;
            float v = ch[r] + cl2[r] + bv2;
            if (rr < n) out[(size_t)rr * 128 + c] = (ushort)f2bf(v);
        }
    }
}

// ---------------- pool ----------------

__global__ void k_gbounds(const int* __restrict__ batch, int* __restrict__ gstart, int n) {
    int g = blockIdx.x * blockDim.x + threadIdx.x;
    if (g > NGRAPHS) return;
    int lo = 0, hi = n;
    while (lo < hi) {
        int mid = (lo + hi) >> 1;
        if (batch[mid] < g) lo = mid + 1; else hi = mid;
    }
    gstart[g] = lo;
}

__global__ __launch_bounds__(256) void k_pool2(const ushort* __restrict__ h,
                                               const int* __restrict__ gstart,
                                               float* __restrict__ out) {
    int g = blockIdx.x;
    int t = threadIdx.x, lane = t & 63, wv = t >> 6;
    int s = gstart[g], e = gstart[g + 1];
    float acc = 0.f;
    for (int i = s + wv; i < e; i += 4) {
        uint v = h[(size_t)i * 64 + lane];
        acc += __uint_as_float(v << 16);
    }
    __shared__ float red[4][64];
    red[wv][lane] = acc;
    __syncthreads();
    if (wv == 0) {
        float tot = red[0][lane] + red[1][lane] + red[2][lane] + red[3][lane];
        float c = (float)(e - s);
        out[g * 64 + lane] = tot / fmaxf(c, 1.0f);
    }
}

// ---------------- launcher ----------------

extern "C" void kernel_launch(void* const* d_in, const int* in_sizes, int n_in,
                              void* d_out, int out_size, void* d_ws, size_t ws_size,
                              hipStream_t stream) {
    const float* x = (const float*)d_in[0];
    const int* ei = (const int*)d_in[1];
    const int* batch = (const int*)d_in[2];
    const float* wn0 = (const float*)d_in[3];
    const float* ws0 = (const float*)d_in[4];
    const float* b0 = (const float*)d_in[5];
    const float* wn1 = (const float*)d_in[6];
    const float* ws1 = (const float*)d_in[7];
    const float* b1 = (const float*)d_in[8];
    const float* wn2 = (const float*)d_in[9];
    const float* ws2 = (const float*)d_in[10];
    const float* b2 = (const float*)d_in[11];

    const int n = in_sizes[0] / 128;  // 100000
    const int nE = in_sizes[1] / 2;   // 1600000
    const int* src = ei;
    const int* dst = ei + nE;
    const int NB = (n + 255) >> 8;    // 391 buckets

    char* p = (char*)d_ws;
    auto alloc = [&](size_t bytes) {
        void* r = (void*)p;
        p += (bytes + 255) & ~(size_t)255;
        return r;
    };
    int* bcur = (int*)alloc((size_t)NB * 4);
    uint* pairs = (uint*)alloc((size_t)NB * BCAP * 4);
    int* col = (int*)alloc((size_t)NB * BCAP * 4);
    int* row_start = (int*)alloc((size_t)NB * 256 * 4);
    int* row_end = (int*)alloc((size_t)NB * 256 * 4);
    float* rdeg = (float*)alloc((size_t)NB * 256 * 4);
    int* gstart = (int*)alloc((size_t)(NGRAPHS + 1) * 4);
    short* whi0 = (short*)alloc(128 * 256 * 2);
    short* wlo0 = (short*)alloc(128 * 256 * 2);
    short* whi1 = (short*)alloc(128 * 256 * 2);
    short* wlo1 = (short*)alloc(128 * 256 * 2);
    short* whi2 = (short*)alloc(128 * 128 * 2);
    short* wlo2 = (short*)alloc(128 * 128 * 2);
    ushort* xb = (ushort*)alloc((size_t)n * 128 * 2);
    ushort* meanb = (ushort*)alloc((size_t)n * 128 * 2);
    ushort* h1 = (ushort*)alloc((size_t)n * 128 * 2);
    ushort* t2 = (ushort*)alloc((size_t)n * 128 * 2);
    ushort* h3 = (ushort*)alloc((size_t)n * 64 * 2);

    (void)hipMemsetAsync(bcur, 0, (size_t)NB * 4, stream);

    const int tb = 256;

    k_bscatter<<<(nE + 4095) / 4096, tb, 0, stream>>>(src, dst, bcur, pairs, nE, NB);
    k_bbuild<<<NB, tb, 0, stream>>>(bcur, pairs, row_start, row_end, rdeg, col, n);

    k_cast<<<((n * 128 / 4) + 255) / 256, 256, 0, stream>>>(x, xb, n * 128 / 4);

    k_wprep<<<(128 * 256 + 255) / 256, 256, 0, stream>>>(wn0, ws0, whi0, wlo0, 128);
    k_wprep<<<(128 * 256 + 255) / 256, 256, 0, stream>>>(wn1, ws1, whi1, wlo1, 128);
    k_wprep2<<<(128 * 128 + 255) / 256, 256, 0, stream>>>(wn2, ws2, whi2, wlo2);

    k_gbounds<<<3, 256, 0, stream>>>(batch, gstart, n);

    const int aggGrid = ((n * 64) + tb - 1) / tb;
    const int nTiles = (n + 15) / 16;
    const int CH = 13;
    const int tGrid = (nTiles + CH - 1) / CH;

    // layer 0
    k_agg<<<aggGrid, tb, 0, stream>>>(xb, row_start, row_end, col, rdeg, meanb, n);
    k_transform2<true, 13><<<tGrid, 512, 0, stream>>>(
        meanb, xb, (const bf16x8*)whi0, (const bf16x8*)wlo0, b0, h1, n, nTiles);
    // layer 1 agg, then fused (L1 transform -> h2 tile in LDS -> L2 commuted transform)
    k_agg<<<aggGrid, tb, 0, stream>>>(h1, row_start, row_end, col, rdeg, meanb, n);
    k_transform_fused<13><<<tGrid, 512, 0, stream>>>(
        meanb, h1, (const bf16x8*)whi1, (const bf16x8*)wlo1, b1,
        (const bf16x8*)whi2, (const bf16x8*)wlo2, b2, t2, n, nTiles);
    // layer 2 aggregation on t2
    k_agg2<<<aggGrid, tb, 0, stream>>>(t2, row_start, row_end, col, rdeg, h3, n);

    // pool -> d_out
    k_pool2<<<NGRAPHS, 256, 0, stream>>>(h3, gstart, (float*)d_out);
}

// Round 11
// 325.320 us; speedup vs baseline: 2.2877x; 1.1170x over previous
//
#include <hip/hip_runtime.h>
#include <hip/hip_bf16.h>

#define NGRAPHS 512
#define BCAP 8192

typedef __attribute__((ext_vector_type(8))) short bf16x8;
typedef __attribute__((ext_vector_type(4))) float f32x4;

__device__ inline short f2bf(float x) {
    __hip_bfloat16 h = __float2bfloat16(x);
    return *(short*)&h;
}
__device__ inline float bflo(uint v) { return __uint_as_float(v << 16); }
__device__ inline float bfhi(uint v) { return __uint_as_float(v & 0xffff0000u); }

// ---------------- bucket-sort CSR build ----------------

__global__ __launch_bounds__(256) void k_bscatter(const int* __restrict__ src,
                                                  const int* __restrict__ dst,
                                                  int* __restrict__ bcur,
                                                  uint* __restrict__ pairs,
                                                  int nE, int NB) {
    __shared__ int cnt[512];
    __shared__ int gbase[512];
    const int t = threadIdx.x;
    const int seg0 = blockIdx.x * 4096;

    for (int l = t; l < NB; l += 256) cnt[l] = 0;
    __syncthreads();

    int sv[16], bv[16], rv[16];
#pragma unroll
    for (int k = 0; k < 16; ++k) {
        int e = seg0 + k * 256 + t;
        if (e < nE) {
            int d = dst[e];
            bv[k] = d >> 8;
            rv[k] = atomicAdd(&cnt[bv[k]], 1);
            sv[k] = src[e] | ((d & 255) << 20);
        } else {
            bv[k] = -1;
        }
    }
    __syncthreads();
    for (int l = t; l < NB; l += 256) {
        int c = cnt[l];
        gbase[l] = (c > 0) ? atomicAdd(&bcur[l], c) : 0;
    }
    __syncthreads();
#pragma unroll
    for (int k = 0; k < 16; ++k) {
        if (bv[k] >= 0) {
            int pos = gbase[bv[k]] + rv[k];
            if (pos < BCAP) pairs[(size_t)bv[k] * BCAP + pos] = (uint)sv[k];
        }
    }
}

// round-8 bbuild (no sort - sort was a measured null on FETCH and cost ~40us)

__global__ __launch_bounds__(256) void k_bbuild(const int* __restrict__ bcur,
                                                const uint* __restrict__ pairs,
                                                int* __restrict__ row_start,
                                                int* __restrict__ row_end,
                                                float* __restrict__ rdeg,
                                                int* __restrict__ col, int n) {
    __shared__ int s[256];
    __shared__ int cur[256];
    const int b = blockIdx.x;
    const int t = threadIdx.x;
    const uint* bp = pairs + (size_t)b * BCAP;
    int cnt = bcur[b];
    if (cnt > BCAP) cnt = BCAP;

    s[t] = 0;
    __syncthreads();
    for (int i = t; i < cnt; i += 256) {
        int local = bp[i] >> 20;
        atomicAdd(&s[local], 1);
    }
    __syncthreads();
    int my = s[t];
    for (int off = 1; off < 256; off <<= 1) {
        int v = (t >= off) ? s[t - off] : 0;
        __syncthreads();
        s[t] += v;
        __syncthreads();
    }
    int excl = s[t] - my;
    int v = b * 256 + t;
    if (v < n) {
        row_start[v] = b * BCAP + excl;
        row_end[v] = b * BCAP + excl + my;
        rdeg[v] = 1.0f / (float)(my > 1 ? my : 1);
    }
    cur[t] = excl;
    __syncthreads();
    for (int i = t; i < cnt; i += 256) {
        uint u = bp[i];
        int local = u >> 20;
        int pos = atomicAdd(&cur[local], 1);
        col[(size_t)b * BCAP + pos] = (int)(u & 0xFFFFFu);
    }
}

// ---------------- f32 -> bf16 cast ----------------

__global__ __launch_bounds__(256) void k_cast(const float* __restrict__ x,
                                              ushort* __restrict__ xb, int total4) {
    int i = blockIdx.x * 256 + threadIdx.x;
    if (i >= total4) return;
    float4 v = ((const float4*)x)[i];
    ushort4 o;
    o.x = (ushort)f2bf(v.x);
    o.y = (ushort)f2bf(v.y);
    o.z = (ushort)f2bf(v.z);
    o.w = (ushort)f2bf(v.w);
    ((ushort4*)xb)[i] = o;
}

// ---------------- mean aggregation (128 ch) ----------------

__global__ __launch_bounds__(256) void k_agg(const ushort* __restrict__ h,
                                             const int* __restrict__ row_start,
                                             const int* __restrict__ row_end,
                                             const int* __restrict__ col,
                                             const float* __restrict__ rdeg,
                                             ushort* __restrict__ out, int n) {
    int w = (blockIdx.x * blockDim.x + threadIdx.x) >> 6;
    int lane = threadIdx.x & 63;
    if (w >= n) return;
    int s = row_start[w], e = row_end[w];
    int grp = lane >> 4;
    int cl = lane & 15;

    float a0 = 0.f, a1 = 0.f, a2 = 0.f, a3 = 0.f, a4 = 0.f, a5 = 0.f, a6 = 0.f, a7 = 0.f;

    if (e > s) {
        int cfirst = col[s];
        for (int j = s; j < e; j += 8) {
            int j0 = j + grp, j1 = j + 4 + grp;
            bool ok0 = j0 < e, ok1 = j1 < e;
            int c0 = ok0 ? col[j0] : cfirst;
            int c1 = ok1 ? col[j1] : cfirst;
            uint4 r0 = *(const uint4*)(h + (size_t)c0 * 128 + cl * 8);
            uint4 r1 = *(const uint4*)(h + (size_t)c1 * 128 + cl * 8);
            if (ok0) {
                a0 += bflo(r0.x); a1 += bfhi(r0.x);
                a2 += bflo(r0.y); a3 += bfhi(r0.y);
                a4 += bflo(r0.z); a5 += bfhi(r0.z);
                a6 += bflo(r0.w); a7 += bfhi(r0.w);
            }
            if (ok1) {
                a0 += bflo(r1.x); a1 += bfhi(r1.x);
                a2 += bflo(r1.y); a3 += bfhi(r1.y);
                a4 += bflo(r1.z); a5 += bfhi(r1.z);
                a6 += bflo(r1.w); a7 += bfhi(r1.w);
            }
        }
        a0 += __shfl_xor(a0, 16); a1 += __shfl_xor(a1, 16);
        a2 += __shfl_xor(a2, 16); a3 += __shfl_xor(a3, 16);
        a4 += __shfl_xor(a4, 16); a5 += __shfl_xor(a5, 16);
        a6 += __shfl_xor(a6, 16); a7 += __shfl_xor(a7, 16);
        a0 += __shfl_xor(a0, 32); a1 += __shfl_xor(a1, 32);
        a2 += __shfl_xor(a2, 32); a3 += __shfl_xor(a3, 32);
        a4 += __shfl_xor(a4, 32); a5 += __shfl_xor(a5, 32);
        a6 += __shfl_xor(a6, 32); a7 += __shfl_xor(a7, 32);
    }

    if (grp == 0) {
        float r = rdeg[w];
        uint4 o;
        o.x = (uint)(ushort)f2bf(a0 * r) | ((uint)(ushort)f2bf(a1 * r) << 16);
        o.y = (uint)(ushort)f2bf(a2 * r) | ((uint)(ushort)f2bf(a3 * r) << 16);
        o.z = (uint)(ushort)f2bf(a4 * r) | ((uint)(ushort)f2bf(a5 * r) << 16);
        o.w = (uint)(ushort)f2bf(a6 * r) | ((uint)(ushort)f2bf(a7 * r) << 16);
        *(uint4*)(out + (size_t)w * 128 + cl * 8) = o;
    }
}

// ---------------- layer-2 aggregation on t2 = [tn|ts] ----------------

__global__ __launch_bounds__(256) void k_agg2(const ushort* __restrict__ t2,
                                              const int* __restrict__ row_start,
                                              const int* __restrict__ row_end,
                                              const int* __restrict__ col,
                                              const float* __restrict__ rdeg,
                                              ushort* __restrict__ out, int n) {
    int w = (blockIdx.x * blockDim.x + threadIdx.x) >> 6;
    int lane = threadIdx.x & 63;
    if (w >= n) return;
    int s = row_start[w], e = row_end[w];
    int grp = lane >> 4;
    int cl = lane & 15;

    float a0 = 0.f, a1 = 0.f, a2 = 0.f, a3 = 0.f;

    if (e > s) {
        int cfirst = col[s];
        for (int j = s; j < e; j += 8) {
            int j0 = j + grp, j1 = j + 4 + grp;
            bool ok0 = j0 < e, ok1 = j1 < e;
            int c0 = ok0 ? col[j0] : cfirst;
            int c1 = ok1 ? col[j1] : cfirst;
            uint2 r0 = *(const uint2*)(t2 + (size_t)c0 * 128 + cl * 4);
            uint2 r1 = *(const uint2*)(t2 + (size_t)c1 * 128 + cl * 4);
            if (ok0) {
                a0 += bflo(r0.x); a1 += bfhi(r0.x);
                a2 += bflo(r0.y); a3 += bfhi(r0.y);
            }
            if (ok1) {
                a0 += bflo(r1.x); a1 += bfhi(r1.x);
                a2 += bflo(r1.y); a3 += bfhi(r1.y);
            }
        }
        a0 += __shfl_xor(a0, 16); a1 += __shfl_xor(a1, 16);
        a2 += __shfl_xor(a2, 16); a3 += __shfl_xor(a3, 16);
        a0 += __shfl_xor(a0, 32); a1 += __shfl_xor(a1, 32);
        a2 += __shfl_xor(a2, 32); a3 += __shfl_xor(a3, 32);
    }

    if (grp == 0) {
        float r = rdeg[w];
        uint2 tsv = *(const uint2*)(t2 + (size_t)w * 128 + 64 + cl * 4);
        float t0 = bflo(tsv.x), t1 = bfhi(tsv.x);
        float t2v = bflo(tsv.y), t3 = bfhi(tsv.y);
        uint2 o;
        o.x = (uint)(ushort)f2bf(a0 * r + t0) | ((uint)(ushort)f2bf(a1 * r + t1) << 16);
        o.y = (uint)(ushort)f2bf(a2 * r + t2v) | ((uint)(ushort)f2bf(a3 * r + t3) << 16);
        *(uint2*)(out + (size_t)w * 64 + cl * 4) = o;
    }
}

// ---------------- weight prep ----------------

__global__ void k_wprep(const float* __restrict__ wn, const float* __restrict__ ws,
                        short* __restrict__ whi, short* __restrict__ wlo, int outc) {
    int i = blockIdx.x * 256 + threadIdx.x;
    if (i >= outc * 256) return;
    int c = i >> 8, k = i & 255;
    float w = (k < 128) ? wn[c * 128 + k] : ws[c * 128 + k - 128];
    short hi = f2bf(w);
    __hip_bfloat16 hb = *(__hip_bfloat16*)&hi;
    float hif = __bfloat162float(hb);
    whi[i] = hi;
    wlo[i] = f2bf(w - hif);
}

__global__ void k_wprep2(const float* __restrict__ wn, const float* __restrict__ ws,
                         short* __restrict__ whi, short* __restrict__ wlo) {
    int i = blockIdx.x * 256 + threadIdx.x;
    if (i >= 128 * 128) return;
    int c = i >> 7, k = i & 127;
    float w = (c < 64) ? wn[c * 128 + k] : ws[(c - 64) * 128 + k];
    short hi = f2bf(w);
    __hip_bfloat16 hb = *(__hip_bfloat16*)&hi;
    float hif = __bfloat162float(hb);
    whi[i] = hi;
    wlo[i] = f2bf(w - hif);
}

// ---------------- pipelined LDS-staged MFMA transform (layer 0) ----------------

template <bool RELU, int CHUNK>
__global__ __launch_bounds__(512) void k_transform2(
    const ushort* __restrict__ meanbuf, const ushort* __restrict__ hbuf,
    const bf16x8* __restrict__ whi, const bf16x8* __restrict__ wlo,
    const float* __restrict__ bias, ushort* __restrict__ out, int n, int nTiles) {
    constexpr int ROWB = 512;
    __shared__ ushort lds[2][16 * 256];

    const int t = threadIdx.x;
    const int wave = t >> 6, lane = t & 63;
    const int lmod = lane & 15, lgrp = lane >> 4;
    const int c = wave * 16 + lmod;

    bf16x8 bh[8], bl[8];
#pragma unroll
    for (int ks = 0; ks < 8; ++ks) {
        int idx = c * 32 + ks * 4 + lgrp;
        bh[ks] = whi[idx];
        bl[ks] = wlo[idx];
    }
    float bv = bias[c];

    const int srow = t >> 5;
    const int seg = t & 31;
    const int tile0 = blockIdx.x * CHUNK;
    if (tile0 >= nTiles) return;
    const int nt = (nTiles - tile0 < CHUNK) ? (nTiles - tile0) : CHUNK;
    const int swr = (srow * ROWB + seg * 16) ^ ((srow & 7) << 4);

    uint4 R;
    {
        int m = tile0 * 16 + srow; if (m >= n) m = n - 1;
        const ushort* sp = (seg < 16) ? (meanbuf + (size_t)m * 128 + seg * 8)
                                      : (hbuf + (size_t)m * 128 + (seg - 16) * 8);
        R = *(const uint4*)sp;
    }
    *(uint4*)((char*)lds[0] + swr) = R;
    {
        int m = (tile0 + 1) * 16 + srow; if (m >= n) m = n - 1;
        const ushort* sp = (seg < 16) ? (meanbuf + (size_t)m * 128 + seg * 8)
                                      : (hbuf + (size_t)m * 128 + (seg - 16) * 8);
        R = *(const uint4*)sp;
    }

    for (int tt = 0; tt < nt; ++tt) {
        __syncthreads();
        if (tt + 1 < nt) *(uint4*)((char*)lds[(tt + 1) & 1] + swr) = R;
        if (tt + 2 < nt) {
            int m = (tile0 + tt + 2) * 16 + srow; if (m >= n) m = n - 1;
            const ushort* sp = (seg < 16) ? (meanbuf + (size_t)m * 128 + seg * 8)
                                          : (hbuf + (size_t)m * 128 + (seg - 16) * 8);
            R = *(const uint4*)sp;
        }

        bf16x8 af[8];
#pragma unroll
        for (int ks = 0; ks < 8; ++ks) {
            int byte = (lmod * ROWB + ks * 64 + lgrp * 16) ^ ((lmod & 7) << 4);
            af[ks] = *(const bf16x8*)((const char*)lds[tt & 1] + byte);
        }
        f32x4 ah = {0.f, 0.f, 0.f, 0.f}, al = {0.f, 0.f, 0.f, 0.f};
#pragma unroll
        for (int ks = 0; ks < 8; ++ks) {
            ah = __builtin_amdgcn_mfma_f32_16x16x32_bf16(af[ks], bh[ks], ah, 0, 0, 0);
            al = __builtin_amdgcn_mfma_f32_16x16x32_bf16(af[ks], bl[ks], al, 0, 0, 0);
        }
        int row0 = (tile0 + tt) * 16;
#pragma unroll
        for (int r = 0; r < 4; ++r) {
            int rr = row0 + lgrp * 4 + r;
            float v = ah[r] + al[r] + bv;
            if (RELU) v = fmaxf(v, 0.f);
            if (rr < n) out[(size_t)rr * 128 + c] = (ushort)f2bf(v);
        }
    }
}

// ---------------- fused layer-1 transform + commuted layer-2 transform ----------------

template <int CHUNK>
__global__ __launch_bounds__(512) void k_transform_fused(
    const ushort* __restrict__ meanbuf, const ushort* __restrict__ hbuf,
    const bf16x8* __restrict__ whi1, const bf16x8* __restrict__ wlo1,
    const float* __restrict__ bias1,
    const bf16x8* __restrict__ whi2, const bf16x8* __restrict__ wlo2,
    const float* __restrict__ bias2,
    ushort* __restrict__ out, int n, int nTiles) {
    constexpr int ROWB = 512;
    __shared__ ushort lds[2][16 * 256];
    __shared__ ushort hlds[16 * 128];

    const int t = threadIdx.x;
    const int wave = t >> 6, lane = t & 63;
    const int lmod = lane & 15, lgrp = lane >> 4;
    const int c = wave * 16 + lmod;

    bf16x8 b1h[8], b1l[8], b2h[4], b2l[4];
#pragma unroll
    for (int ks = 0; ks < 8; ++ks) {
        int idx = c * 32 + ks * 4 + lgrp;
        b1h[ks] = whi1[idx];
        b1l[ks] = wlo1[idx];
    }
#pragma unroll
    for (int ks = 0; ks < 4; ++ks) {
        int idx = c * 16 + ks * 4 + lgrp;
        b2h[ks] = whi2[idx];
        b2l[ks] = wlo2[idx];
    }
    float bv1 = bias1[c];
    float bv2 = (c >= 64) ? bias2[c - 64] : 0.f;

    const int srow = t >> 5;
    const int seg = t & 31;
    const int tile0 = blockIdx.x * CHUNK;
    if (tile0 >= nTiles) return;
    const int nt = (nTiles - tile0 < CHUNK) ? (nTiles - tile0) : CHUNK;
    const int swr = (srow * ROWB + seg * 16) ^ ((srow & 7) << 4);

    uint4 R;
    {
        int m = tile0 * 16 + srow; if (m >= n) m = n - 1;
        const ushort* sp = (seg < 16) ? (meanbuf + (size_t)m * 128 + seg * 8)
                                      : (hbuf + (size_t)m * 128 + (seg - 16) * 8);
        R = *(const uint4*)sp;
    }
    *(uint4*)((char*)lds[0] + swr) = R;
    {
        int m = (tile0 + 1) * 16 + srow; if (m >= n) m = n - 1;
        const ushort* sp = (seg < 16) ? (meanbuf + (size_t)m * 128 + seg * 8)
                                      : (hbuf + (size_t)m * 128 + (seg - 16) * 8);
        R = *(const uint4*)sp;
    }

    for (int tt = 0; tt < nt; ++tt) {
        __syncthreads();
        if (tt + 1 < nt) *(uint4*)((char*)lds[(tt + 1) & 1] + swr) = R;
        if (tt + 2 < nt) {
            int m = (tile0 + tt + 2) * 16 + srow; if (m >= n) m = n - 1;
            const ushort* sp = (seg < 16) ? (meanbuf + (size_t)m * 128 + seg * 8)
                                          : (hbuf + (size_t)m * 128 + (seg - 16) * 8);
            R = *(const uint4*)sp;
        }

        // stage 1: K=256 MFMA
        bf16x8 af[8];
#pragma unroll
        for (int ks = 0; ks < 8; ++ks) {
            int byte = (lmod * ROWB + ks * 64 + lgrp * 16) ^ ((lmod & 7) << 4);
            af[ks] = *(const bf16x8*)((const char*)lds[tt & 1] + byte);
        }
        f32x4 ah = {0.f, 0.f, 0.f, 0.f}, al = {0.f, 0.f, 0.f, 0.f};
#pragma unroll
        for (int ks = 0; ks < 8; ++ks) {
            ah = __builtin_amdgcn_mfma_f32_16x16x32_bf16(af[ks], b1h[ks], ah, 0, 0, 0);
            al = __builtin_amdgcn_mfma_f32_16x16x32_bf16(af[ks], b1l[ks], al, 0, 0, 0);
        }
#pragma unroll
        for (int r = 0; r < 4; ++r) {
            int rr16 = lgrp * 4 + r;
            float v = fmaxf(ah[r] + al[r] + bv1, 0.f);
            int byte = ((rr16 * 256 + (c >> 3) * 16) ^ ((rr16 & 7) << 4)) + (c & 7) * 2;
            *(ushort*)((char*)hlds + byte) = (ushort)f2bf(v);
        }
        __syncthreads();  // h2 tile complete

        // stage 2: K=128 MFMA from hlds
        bf16x8 af2[4];
#pragma unroll
        for (int ks = 0; ks < 4; ++ks) {
            int byte = (lmod * 256 + ks * 64 + lgrp * 16) ^ ((lmod & 7) << 4);
            af2[ks] = *(const bf16x8*)((const char*)hlds + byte);
        }
        f32x4 ch = {0.f, 0.f, 0.f, 0.f}, cl2 = {0.f, 0.f, 0.f, 0.f};
#pragma unroll
        for (int ks = 0; ks < 4; ++ks) {
            ch = __builtin_amdgcn_mfma_f32_16x16x32_bf16(af2[ks], b2h[ks], ch, 0, 0, 0);
            cl2 = __builtin_amdgcn_mfma_f32_16x16x32_bf16(af2[ks], b2l[ks], cl2, 0, 0, 0);
        }
        int row0 = (tile0 + tt) * 16;
#pragma unroll
        for (int r = 0; r < 4; ++r) {
            int rr = row0 + lgrp * 4 + r;
            float v = ch[r] + cl2[r] + bv2;
            if (rr < n) out[(size_t)rr * 128 + c] = (ushort)f2bf(v);
        }
    }
}

// ---------------- pool ----------------

__global__ void k_gbounds(const int* __restrict__ batch, int* __restrict__ gstart, int n) {
    int g = blockIdx.x * blockDim.x + threadIdx.x;
    if (g > NGRAPHS) return;
    int lo = 0, hi = n;
    while (lo < hi) {
        int mid = (lo + hi) >> 1;
        if (batch[mid] < g) lo = mid + 1; else hi = mid;
    }
    gstart[g] = lo;
}

__global__ __launch_bounds__(256) void k_pool2(const ushort* __restrict__ h,
                                               const int* __restrict__ gstart,
                                               float* __restrict__ out) {
    int g = blockIdx.x;
    int t = threadIdx.x, lane = t & 63, wv = t >> 6;
    int s = gstart[g], e = gstart[g + 1];
    float acc = 0.f;
    for (int i = s + wv; i < e; i += 4) {
        uint v = h[(size_t)i * 64 + lane];
        acc += __uint_as_float(v << 16);
    }
    __shared__ float red[4][64];
    red[wv][lane] = acc;
    __syncthreads();
    if (wv == 0) {
        float tot = red[0][lane] + red[1][lane] + red[2][lane] + red[3][lane];
        float c = (float)(e - s);
        out[g * 64 + lane] = tot / fmaxf(c, 1.0f);
    }
}

// ---------------- launcher ----------------

extern "C" void kernel_launch(void* const* d_in, const int* in_sizes, int n_in,
                              void* d_out, int out_size, void* d_ws, size_t ws_size,
                              hipStream_t stream) {
    const float* x = (const float*)d_in[0];
    const int* ei = (const int*)d_in[1];
    const int* batch = (const int*)d_in[2];
    const float* wn0 = (const float*)d_in[3];
    const float* ws0 = (const float*)d_in[4];
    const float* b0 = (const float*)d_in[5];
    const float* wn1 = (const float*)d_in[6];
    const float* ws1 = (const float*)d_in[7];
    const float* b1 = (const float*)d_in[8];
    const float* wn2 = (const float*)d_in[9];
    const float* ws2 = (const float*)d_in[10];
    const float* b2 = (const float*)d_in[11];

    const int n = in_sizes[0] / 128;  // 100000
    const int nE = in_sizes[1] / 2;   // 1600000
    const int* src = ei;
    const int* dst = ei + nE;
    const int NB = (n + 255) >> 8;    // 391 buckets

    char* p = (char*)d_ws;
    auto alloc = [&](size_t bytes) {
        void* r = (void*)p;
        p += (bytes + 255) & ~(size_t)255;
        return r;
    };
    int* bcur = (int*)alloc((size_t)NB * 4);
    uint* pairs = (uint*)alloc((size_t)NB * BCAP * 4);
    int* col = (int*)alloc((size_t)NB * BCAP * 4);
    int* row_start = (int*)alloc((size_t)NB * 256 * 4);
    int* row_end = (int*)alloc((size_t)NB * 256 * 4);
    float* rdeg = (float*)alloc((size_t)NB * 256 * 4);
    int* gstart = (int*)alloc((size_t)(NGRAPHS + 1) * 4);
    short* whi0 = (short*)alloc(128 * 256 * 2);
    short* wlo0 = (short*)alloc(128 * 256 * 2);
    short* whi1 = (short*)alloc(128 * 256 * 2);
    short* wlo1 = (short*)alloc(128 * 256 * 2);
    short* whi2 = (short*)alloc(128 * 128 * 2);
    short* wlo2 = (short*)alloc(128 * 128 * 2);
    ushort* xb = (ushort*)alloc((size_t)n * 128 * 2);
    ushort* meanb = (ushort*)alloc((size_t)n * 128 * 2);
    ushort* h1 = (ushort*)alloc((size_t)n * 128 * 2);
    ushort* t2 = (ushort*)alloc((size_t)n * 128 * 2);
    ushort* h3 = (ushort*)alloc((size_t)n * 64 * 2);

    (void)hipMemsetAsync(bcur, 0, (size_t)NB * 4, stream);

    const int tb = 256;

    k_bscatter<<<(nE + 4095) / 4096, tb, 0, stream>>>(src, dst, bcur, pairs, nE, NB);
    k_bbuild<<<NB, tb, 0, stream>>>(bcur, pairs, row_start, row_end, rdeg, col, n);

    k_cast<<<((n * 128 / 4) + 255) / 256, 256, 0, stream>>>(x, xb, n * 128 / 4);

    k_wprep<<<(128 * 256 + 255) / 256, 256, 0, stream>>>(wn0, ws0, whi0, wlo0, 128);
    k_wprep<<<(128 * 256 + 255) / 256, 256, 0, stream>>>(wn1, ws1, whi1, wlo1, 128);
    k_wprep2<<<(128 * 128 + 255) / 256, 256, 0, stream>>>(wn2, ws2, whi2, wlo2);

    k_gbounds<<<3, 256, 0, stream>>>(batch, gstart, n);

    const int aggGrid = ((n * 64) + tb - 1) / tb;
    const int nTiles = (n + 15) / 16;
    const int CH = 13;
    const int tGrid = (nTiles + CH - 1) / CH;

    // layer 0
    k_agg<<<aggGrid, tb, 0, stream>>>(xb, row_start, row_end, col, rdeg, meanb, n);
    k_transform2<true, 13><<<tGrid, 512, 0, stream>>>(
        meanb, xb, (const bf16x8*)whi0, (const bf16x8*)wlo0, b0, h1, n, nTiles);
    // layer 1 agg, then fused (L1 transform -> h2 tile in LDS -> L2 commuted transform)
    k_agg<<<aggGrid, tb, 0, stream>>>(h1, row_start, row_end, col, rdeg, meanb, n);
    k_transform_fused<13><<<tGrid, 512, 0, stream>>>(
        meanb, h1, (const bf16x8*)whi1, (const bf16x8*)wlo1, b1,
        (const bf16x8*)whi2, (const bf16x8*)wlo2, b2, t2, n, nTiles);
    // layer 2 aggregation on t2
    k_agg2<<<aggGrid, tb, 0, stream>>>(t2, row_start, row_end, col, rdeg, h3, n);

    // pool -> d_out
    k_pool2<<<NGRAPHS, 256, 0, stream>>>(h3, gstart, (float*)d_out);
}